// Round 1
// baseline (83.204 us; speedup 1.0000x reference)
//
#include <hip/hip_runtime.h>
#include <math.h>

#define NCOL 8192
#define NROW 4096
#define KSEL 819
#define TPB 256
#define VPT 8   // float4 per thread (32 elements/thread)

// Per-column boost factors, recomputed every launch (deterministic).
__device__ float g_boost[NCOL];

__global__ void boost_kernel(const float* __restrict__ duty) {
    int i = blockIdx.x * blockDim.x + threadIdx.x;
    if (i < NCOL) {
        // target_density = 819/8192 (exactly representable), boost_strength = 1
        float diff = (0.0999755859375f - duty[i]) * 1.0f;   // f32, like reference
        g_boost[i] = (float)exp((double)diff);               // correctly-rounded f32 exp
    }
}

__device__ __forceinline__ unsigned f2k(float f) {
    // monotone float -> uint map (total order)
    unsigned u = __float_as_uint(f);
    return (u & 0x80000000u) ? ~u : (u | 0x80000000u);
}

__global__ __launch_bounds__(TPB) void kwinners_kernel(const float* __restrict__ x,
                                                       float* __restrict__ out) {
    __shared__ __align__(16) unsigned lds_key[NCOL]; // 32 KB, index order
    __shared__ int lds_hist[256];
    __shared__ int lds_wtot[4];
    __shared__ unsigned lds_prefix;
    __shared__ int lds_R;
    __shared__ int lds_E;

    const int t = threadIdx.x;
    const int row = blockIdx.x;
    const int lane = t & 63;
    const int w = t >> 6;

    const float4* x4 = (const float4*)(x + (size_t)row * NCOL);
    const float4* b4 = (const float4*)g_boost;
    uint4* k4 = (uint4*)lds_key;

    float4 xv[VPT];
    unsigned kr[VPT][4];

#pragma unroll
    for (int j = 0; j < VPT; ++j) {
        const int v = t + TPB * j;          // float4 index; element col = 4v+c
        float4 xx = x4[v];
        float4 bb = b4[v];
        xv[j] = xx;
        unsigned k0 = f2k(xx.x * bb.x);
        unsigned k1 = f2k(xx.y * bb.y);
        unsigned k2 = f2k(xx.z * bb.z);
        unsigned k3 = f2k(xx.w * bb.w);
        kr[j][0] = k0; kr[j][1] = k1; kr[j][2] = k2; kr[j][3] = k3;
        uint4 kk; kk.x = k0; kk.y = k1; kk.z = k2; kk.w = k3;
        k4[v] = kk;
    }
    if (t == 0) { lds_prefix = 0u; lds_R = KSEL; lds_E = 0; }

    // 4-pass radix select (MSB->LSB, 8-bit digits): exact key of K-th largest.
    for (int p = 0; p < 4; ++p) {
        lds_hist[t] = 0;
        __syncthreads();                      // covers prefix/R updates + hist zero
        const unsigned pfx = lds_prefix;
        const int R = lds_R;
        const int shift = 24 - 8 * p;
#pragma unroll
        for (int j = 0; j < VPT; ++j) {
#pragma unroll
            for (int c = 0; c < 4; ++c) {
                unsigned key = kr[j][c];
                bool in = (p == 0) || (((key ^ pfx) >> (shift + 8)) == 0u);
                if (in) atomicAdd(&lds_hist[(key >> shift) & 0xFFu], 1);
            }
        }
        __syncthreads();
        const int h = lds_hist[t];
        // wave-level inclusive suffix scan (64 lanes)
        int s = h;
#pragma unroll
        for (int off = 1; off < 64; off <<= 1) {
            int vsh = __shfl_down(s, off);
            if (lane + off < 64) s += vsh;
        }
        if (lane == 0) lds_wtot[w] = s;       // wave total
        __syncthreads();
        int later = 0;
        for (int w2 = w + 1; w2 < 4; ++w2) later += lds_wtot[w2];
        const int Sx = s - h + later;         // count of keys with digit > t (given prefix)
        if (Sx < R && Sx + h >= R) {          // exactly one t satisfies
            lds_prefix = pfx | ((unsigned)t << shift);
            lds_R = R - Sx;
            lds_E = h;
        }
        __syncthreads();
    }

    const unsigned thresh = lds_prefix;       // exact key of the K-th largest
    const int Rf = lds_R;                     // how many equal-to-thresh to keep
    const int E = lds_E;                      // total equal-to-thresh
    if (E > Rf) {                             // tie-break: keep lowest indices (lax.top_k)
        if (t == 0) {
            int seen = 0;
            for (int i = 0; i < NCOL; ++i) {
                if (lds_key[i] == thresh) {
                    ++seen;
                    if (seen > Rf) lds_key[i] = 0u;   // demote (0 < any real key)
                }
            }
        }
        __syncthreads();
    }

    float4* o4 = (float4*)(out + (size_t)row * NCOL);
#pragma unroll
    for (int j = 0; j < VPT; ++j) {
        const int v = t + TPB * j;
        uint4 kk = k4[v];
        float4 xx = xv[j];
        float4 r;
        r.x = (kk.x >= thresh) ? xx.x : 0.0f;
        r.y = (kk.y >= thresh) ? xx.y : 0.0f;
        r.z = (kk.z >= thresh) ? xx.z : 0.0f;
        r.w = (kk.w >= thresh) ? xx.w : 0.0f;
        o4[v] = r;
    }
}

extern "C" void kernel_launch(void* const* d_in, const int* in_sizes, int n_in,
                              void* d_out, int out_size, void* d_ws, size_t ws_size,
                              hipStream_t stream) {
    const float* x = (const float*)d_in[0];        // [4096, 8192] f32
    const float* duty = (const float*)d_in[1];     // [8192] f32
    float* out = (float*)d_out;                    // [4096, 8192] f32
    (void)in_sizes; (void)n_in; (void)out_size; (void)d_ws; (void)ws_size;

    boost_kernel<<<(NCOL + TPB - 1) / TPB, TPB, 0, stream>>>(duty);
    kwinners_kernel<<<NROW, TPB, 0, stream>>>(x, out);
}